// Round 1
// baseline (1804.525 us; speedup 1.0000x reference)
//
#include <hip/hip_runtime.h>

#define BATCH 32
#define NV    10242
#define NF    20480
#define NBB   64          // 2 hemis * 32 batches
#define NSTEPS 10
#define STEPSZ 0.1f
#define EPSV   1e-8f

// ---------------- workspace layout (floats, then ints) ----------------
static constexpr size_t NBBV     = (size_t)NBB * NV;          // 655,488
static constexpr size_t OFF_V    = 0;                          // [NBB,V,3]
static constexpr size_t OFF_SULC = OFF_V    + NBBV * 3;        // [NBB,V]
static constexpr size_t OFF_FEAT = OFF_SULC + NBBV;            // [NBB,V,9] (v,n,lap)
static constexpr size_t OFF_H    = OFF_FEAT + NBBV * 9;        // [NBB,V,16]
static constexpr size_t OFF_CSZ  = OFF_H    + NBBV * 16;       // [NBB,6] center+size
static constexpr size_t OFF_INT  = OFF_CSZ  + (size_t)NBB * 6; // int region starts here
// int region: degF[NV], vface[NV*6], degN[NV], adjN[NV*6]

// ---------------- adjacency build ----------------
__global__ __launch_bounds__(256) void k_zero_deg(int* degF, int* degN) {
    int i = blockIdx.x * 256 + threadIdx.x;
    if (i < NV) { degF[i] = 0; degN[i] = 0; }
}

__global__ __launch_bounds__(256) void k_build(const int* __restrict__ faces,
                                               int* degF, int* vface,
                                               int* degN, int* adjN) {
    int fi = blockIdx.x * 256 + threadIdx.x;
    if (fi >= NF) return;
    int f0 = faces[fi * 3 + 0], f1 = faces[fi * 3 + 1], f2 = faces[fi * 3 + 2];
    int vv[3] = {f0, f1, f2};
#pragma unroll
    for (int c = 0; c < 3; c++) {
        int vtx = vv[c];
        int s = atomicAdd(&degF[vtx], 1);
        vface[vtx * 6 + s] = fi * 3 + c;
        // directed edge vtx -> next corner: appears exactly once over all faces
        int u = vv[(c + 1) % 3];
        int s2 = atomicAdd(&degN[vtx], 1);
        adjN[vtx * 6 + s2] = u;
    }
}

// ---------------- bbox + normalize + sulc init (one block per bb) ----------------
__global__ __launch_bounds__(256) void k_norm(const float* __restrict__ lh,
                                              const float* __restrict__ rh,
                                              float* __restrict__ v,
                                              float* __restrict__ sulc,
                                              float* __restrict__ csz) {
    int bb = blockIdx.x;
    const float* src = (bb < BATCH) ? (lh + (size_t)bb * NV * 3)
                                    : (rh + (size_t)(bb - BATCH) * NV * 3);
    __shared__ float smin[3][256], smax[3][256];
    float mn[3] = {1e30f, 1e30f, 1e30f}, mx[3] = {-1e30f, -1e30f, -1e30f};
    for (int i = threadIdx.x; i < NV; i += 256) {
#pragma unroll
        for (int c = 0; c < 3; c++) {
            float x = src[i * 3 + c];
            mn[c] = fminf(mn[c], x);
            mx[c] = fmaxf(mx[c], x);
        }
    }
#pragma unroll
    for (int c = 0; c < 3; c++) { smin[c][threadIdx.x] = mn[c]; smax[c][threadIdx.x] = mx[c]; }
    __syncthreads();
    for (int s = 128; s > 0; s >>= 1) {
        if (threadIdx.x < s) {
#pragma unroll
            for (int c = 0; c < 3; c++) {
                smin[c][threadIdx.x] = fminf(smin[c][threadIdx.x], smin[c][threadIdx.x + s]);
                smax[c][threadIdx.x] = fmaxf(smax[c][threadIdx.x], smax[c][threadIdx.x + s]);
            }
        }
        __syncthreads();
    }
    float ctr[3], sz[3];
#pragma unroll
    for (int c = 0; c < 3; c++) {
        ctr[c] = 0.5f * (smin[c][0] + smax[c][0]);
        sz[c]  = smax[c][0] - ctr[c];
    }
    if (threadIdx.x == 0) {
#pragma unroll
        for (int c = 0; c < 3; c++) { csz[bb * 6 + c] = ctr[c]; csz[bb * 6 + 3 + c] = sz[c]; }
    }
    float* vd = v + (size_t)bb * NV * 3;
    float* sd = sulc + (size_t)bb * NV;
    for (int i = threadIdx.x; i < NV; i += 256) {
#pragma unroll
        for (int c = 0; c < 3; c++) vd[i * 3 + c] = (src[i * 3 + c] - ctr[c]) / sz[c];
        sd[i] = 0.f;
    }
}

// ---------------- per-step: geometry -> feats[9] = (v, n, 0.5*lap) ----------------
__global__ __launch_bounds__(256) void k_geom(const float* __restrict__ v,
                                              const int* __restrict__ faces,
                                              const int* __restrict__ degF,
                                              const int* __restrict__ vface,
                                              float* __restrict__ feat) {
    int vi = blockIdx.x * 256 + threadIdx.x;
    int bb = blockIdx.y;
    if (vi >= NV) return;
    const float* vb = v + (size_t)bb * NV * 3;
    float sgn = (bb < BATCH) ? 1.f : -1.f;   // rh: reversed winding flips face normals only
    float ax_ = vb[vi * 3 + 0], ay_ = vb[vi * 3 + 1], az_ = vb[vi * 3 + 2];
    float vnx = 0.f, vny = 0.f, vnz = 0.f, lx = 0.f, ly = 0.f, lz = 0.f;
    int d = degF[vi];
    for (int k = 0; k < d; k++) {
        int code = vface[vi * 6 + k];
        int fi = code / 3, ci = code - fi * 3;
        int jn = (ci == 2) ? 0 : ci + 1;     // next corner (B)
        int kn = (ci == 0) ? 2 : ci - 1;     // prev corner (C)
        int iB = faces[fi * 3 + jn], iC = faces[fi * 3 + kn];
        float bx = vb[iB * 3 + 0], by = vb[iB * 3 + 1], bz = vb[iB * 3 + 2];
        float cx = vb[iC * 3 + 0], cy = vb[iC * 3 + 1], cz = vb[iC * 3 + 2];
        float e1x = bx - ax_, e1y = by - ay_, e1z = bz - az_;   // B - A
        float e2x = cx - ax_, e2y = cy - ay_, e2z = cz - az_;   // C - A
        // face normal (cyclic-rotation invariant): cross(B-A, C-A)
        float fnx = e1y * e2z - e1z * e2y;
        float fny = e1z * e2x - e1x * e2z;
        float fnz = e1x * e2y - e1y * e2x;
        vnx += fnx; vny += fny; vnz += fnz;
        float denom = sqrtf(fnx * fnx + fny * fny + fnz * fnz) + EPSV; // = 2*area + eps (all 3 cots)
        // cot at B: edges (C-B, A-B)
        float ux = cx - bx, uy = cy - by, uz = cz - bz;
        float wx = ax_ - bx, wy = ay_ - by, wz = az_ - bz;
        float cB = (ux * wx + uy * wy + uz * wz) / denom;
        // cot at C: edges (A-C, B-C)
        float rx = ax_ - cx, ry = ay_ - cy, rz = az_ - cz;
        float sx = bx - cx, sy = by - cy, sz2 = bz - cz;
        float cC = (rx * sx + ry * sy + rz * sz2) / denom;
        // this corner receives cot(C)*(B-A) + cot(B)*(C-A)
        lx += cC * e1x + cB * e2x;
        ly += cC * e1y + cB * e2y;
        lz += cC * e1z + cB * e2z;
    }
    vnx *= sgn; vny *= sgn; vnz *= sgn;
    float nn = sqrtf(vnx * vnx + vny * vny + vnz * vnz) + EPSV;
    float* fp = feat + ((size_t)bb * NV + vi) * 9;
    fp[0] = ax_; fp[1] = ay_; fp[2] = az_;
    fp[3] = vnx / nn; fp[4] = vny / nn; fp[5] = vnz / nn;
    fp[6] = 0.5f * lx; fp[7] = 0.5f * ly; fp[8] = 0.5f * lz;
}

// ---------------- per-step: layer1  h = relu(feats@W1s + mean_nbr(feats)@W1n + b1) ----------------
__global__ __launch_bounds__(256) void k_layer1(const float* __restrict__ feat,
                                                const int* __restrict__ degN,
                                                const int* __restrict__ adjN,
                                                const float* __restrict__ W1s,
                                                const float* __restrict__ W1n,
                                                const float* __restrict__ b1,
                                                float* __restrict__ h) {
    __shared__ float sWs[144], sWn[144], sb[16];
    int t = threadIdx.x;
    if (t < 144) { sWs[t] = W1s[t]; sWn[t] = W1n[t]; }
    if (t < 16) sb[t] = b1[t];
    __syncthreads();
    int vi = blockIdx.x * 256 + t;
    int bb = blockIdx.y;
    if (vi >= NV) return;
    const float* fb = feat + (size_t)bb * NV * 9;
    float own[9];
#pragma unroll
    for (int i = 0; i < 9; i++) own[i] = fb[(size_t)vi * 9 + i];
    float m[9] = {0, 0, 0, 0, 0, 0, 0, 0, 0};
    int d = degN[vi];
    for (int k = 0; k < d; k++) {
        int u = adjN[vi * 6 + k];
        const float* fu = fb + (size_t)u * 9;
#pragma unroll
        for (int i = 0; i < 9; i++) m[i] += fu[i];
    }
    float inv = 1.f / (float)d;
#pragma unroll
    for (int i = 0; i < 9; i++) m[i] *= inv;
    float* hp = h + ((size_t)bb * NV + vi) * 16;
#pragma unroll
    for (int j = 0; j < 16; j++) {
        float acc = sb[j];
#pragma unroll
        for (int i = 0; i < 9; i++) acc += own[i] * sWs[i * 16 + j] + m[i] * sWn[i * 16 + j];
        hp[j] = fmaxf(acc, 0.f);
    }
}

// ---------------- per-step: layer2 + output head + state update ----------------
__global__ __launch_bounds__(256) void k_layer2(const float* __restrict__ h,
                                                const float* __restrict__ feat,
                                                const int* __restrict__ degN,
                                                const int* __restrict__ adjN,
                                                const float* __restrict__ W2s,
                                                const float* __restrict__ W2n,
                                                const float* __restrict__ b2,
                                                const float* __restrict__ Wo,
                                                const float* __restrict__ bo,
                                                float* __restrict__ v,
                                                float* __restrict__ sulc) {
    __shared__ float sWs[256], sWn[256], sb[16], sWo[48], sbo[3];
    int t = threadIdx.x;
    sWs[t] = W2s[t];
    sWn[t] = W2n[t];
    if (t < 16) sb[t] = b2[t];
    if (t < 48) sWo[t] = Wo[t];
    if (t < 3) sbo[t] = bo[t];
    __syncthreads();
    int vi = blockIdx.x * 256 + t;
    int bb = blockIdx.y;
    if (vi >= NV) return;
    const float* hb = h + (size_t)bb * NV * 16;
    float own[16], m[16];
#pragma unroll
    for (int i = 0; i < 16; i++) { own[i] = hb[(size_t)vi * 16 + i]; m[i] = 0.f; }
    int d = degN[vi];
    for (int k = 0; k < d; k++) {
        int u = adjN[vi * 6 + k];
        const float* hu = hb + (size_t)u * 16;
#pragma unroll
        for (int i = 0; i < 16; i++) m[i] += hu[i];
    }
    float inv = 1.f / (float)d;
#pragma unroll
    for (int i = 0; i < 16; i++) m[i] *= inv;
    float h2[16];
#pragma unroll
    for (int j = 0; j < 16; j++) {
        float acc = sb[j];
#pragma unroll
        for (int i = 0; i < 16; i++) acc += own[i] * sWs[i * 16 + j] + m[i] * sWn[i * 16 + j];
        h2[j] = fmaxf(acc, 0.f);
    }
    float dv[3];
#pragma unroll
    for (int c = 0; c < 3; c++) {
        float acc = sbo[c];
#pragma unroll
        for (int i = 0; i < 16; i++) acc += h2[i] * sWo[i * 3 + c];
        dv[c] = acc;
    }
    size_t vofs = ((size_t)bb * NV + vi) * 3;
    const float* fp = feat + ((size_t)bb * NV + vi) * 9;   // fp[3..5] = n (this step's normals)
    v[vofs + 0] += STEPSZ * dv[0];
    v[vofs + 1] += STEPSZ * dv[1];
    v[vofs + 2] += STEPSZ * dv[2];
    sulc[(size_t)bb * NV + vi] += STEPSZ * (fp[3] * dv[0] + fp[4] * dv[1] + fp[5] * dv[2]);
}

// ---------------- output: (2,B,V,4) = (v*size, sulc) ----------------
__global__ __launch_bounds__(256) void k_out(const float* __restrict__ v,
                                             const float* __restrict__ sulc,
                                             const float* __restrict__ csz,
                                             float* __restrict__ out) {
    int vi = blockIdx.x * 256 + threadIdx.x;
    int bb = blockIdx.y;
    if (vi >= NV) return;
    const float* sz = csz + bb * 6 + 3;
    size_t vofs = ((size_t)bb * NV + vi) * 3;
    float* o = out + ((size_t)bb * NV + vi) * 4;   // bb = hemi*32 + b matches (2,B,...) layout
    o[0] = v[vofs + 0] * sz[0];
    o[1] = v[vofs + 1] * sz[1];
    o[2] = v[vofs + 2] * sz[2];
    o[3] = sulc[(size_t)bb * NV + vi];
}

extern "C" void kernel_launch(void* const* d_in, const int* in_sizes, int n_in,
                              void* d_out, int out_size, void* d_ws, size_t ws_size,
                              hipStream_t stream) {
    const float* lh  = (const float*)d_in[0];
    const float* rh  = (const float*)d_in[1];
    const float* W1s = (const float*)d_in[2];
    const float* W1n = (const float*)d_in[3];
    const float* b1  = (const float*)d_in[4];
    const float* W2s = (const float*)d_in[5];
    const float* W2n = (const float*)d_in[6];
    const float* b2  = (const float*)d_in[7];
    const float* Wo  = (const float*)d_in[8];
    const float* bo  = (const float*)d_in[9];
    const int* faces = (const int*)d_in[10];

    float* ws   = (float*)d_ws;
    float* v    = ws + OFF_V;
    float* sulc = ws + OFF_SULC;
    float* feat = ws + OFF_FEAT;
    float* h    = ws + OFF_H;
    float* csz  = ws + OFF_CSZ;
    int* ibase  = (int*)(ws + OFF_INT);
    int* degF   = ibase;
    int* vface  = ibase + NV;
    int* degN   = ibase + NV + NV * 6;
    int* adjN   = ibase + NV + NV * 6 + NV;

    const int VB = (NV + 255) / 256;   // 41
    dim3 gv(VB, NBB);

    k_zero_deg<<<(NV + 255) / 256, 256, 0, stream>>>(degF, degN);
    k_build<<<(NF + 255) / 256, 256, 0, stream>>>(faces, degF, vface, degN, adjN);
    k_norm<<<NBB, 256, 0, stream>>>(lh, rh, v, sulc, csz);

    for (int s = 0; s < NSTEPS; s++) {
        k_geom<<<gv, 256, 0, stream>>>(v, faces, degF, vface, feat);
        k_layer1<<<gv, 256, 0, stream>>>(feat, degN, adjN, W1s, W1n, b1, h);
        k_layer2<<<gv, 256, 0, stream>>>(h, feat, degN, adjN, W2s, W2n, b2, Wo, bo, v, sulc);
    }
    k_out<<<gv, 256, 0, stream>>>(v, sulc, csz, (float*)d_out);
}

// Round 2
// 1470.833 us; speedup vs baseline: 1.2269x; 1.2269x over previous
//
#include <hip/hip_runtime.h>

#define BATCH 32
#define NV    10242
#define NF    20480
#define NBB   64          // 2 hemis * 32 batches ; lane = bb
#define NSTEPS 10
#define STEPSZ 0.1f
#define EPSV   1e-8f

// ---------------- workspace layout: all state transposed to [V][ch][NBB] ----------------
static constexpr size_t OFF_V    = 0;                              // [V][3][NBB]
static constexpr size_t OFF_SULC = OFF_V    + (size_t)NV * 3 * NBB; // [V][NBB]
static constexpr size_t OFF_FEAT = OFF_SULC + (size_t)NV * NBB;     // [V][9][NBB]
static constexpr size_t OFF_H    = OFF_FEAT + (size_t)NV * 9 * NBB; // [V][16][NBB]
static constexpr size_t OFF_CSZ  = OFF_H    + (size_t)NV * 16 * NBB;// [6][NBB] ctr(3),size(3)
static constexpr size_t OFF_INT  = OFF_CSZ  + 6 * NBB;
// int region: deg[NV], nbrB[NV*6] (next-corner = dedup'd neighbor list), nbrC[NV*6] (prev-corner)

__device__ __forceinline__ int rfl(int x) { return __builtin_amdgcn_readfirstlane(x); }

// ---------------- adjacency build (once per launch) ----------------
__global__ __launch_bounds__(256) void k_zero_deg(int* deg) {
    int i = blockIdx.x * 256 + threadIdx.x;
    if (i < NV) deg[i] = 0;
}

__global__ __launch_bounds__(256) void k_build(const int* __restrict__ faces,
                                               int* deg, int* nbrB, int* nbrC) {
    int fi = blockIdx.x * 256 + threadIdx.x;
    if (fi >= NF) return;
    int vv[3] = {faces[fi * 3 + 0], faces[fi * 3 + 1], faces[fi * 3 + 2]};
#pragma unroll
    for (int c = 0; c < 3; c++) {
        int vtx = vv[c];
        int s = atomicAdd(&deg[vtx], 1);
        // B = next corner (each distinct neighbor appears exactly once over incident faces
        // on a closed oriented manifold), C = prev corner.
        nbrB[vtx * 6 + s] = vv[(c + 1) % 3];
        nbrC[vtx * 6 + s] = vv[(c + 2) % 3];
    }
}

// ---------------- bbox + normalize + transpose-in (one block per bb) ----------------
__global__ __launch_bounds__(256) void k_norm(const float* __restrict__ lh,
                                              const float* __restrict__ rh,
                                              float* __restrict__ v,
                                              float* __restrict__ sulc,
                                              float* __restrict__ csz) {
    int bb = blockIdx.x;
    const float* src = (bb < BATCH) ? (lh + (size_t)bb * NV * 3)
                                    : (rh + (size_t)(bb - BATCH) * NV * 3);
    __shared__ float smin[3][256], smax[3][256];
    float mn[3] = {1e30f, 1e30f, 1e30f}, mx[3] = {-1e30f, -1e30f, -1e30f};
    for (int i = threadIdx.x; i < NV; i += 256) {
#pragma unroll
        for (int c = 0; c < 3; c++) {
            float x = src[i * 3 + c];
            mn[c] = fminf(mn[c], x);
            mx[c] = fmaxf(mx[c], x);
        }
    }
#pragma unroll
    for (int c = 0; c < 3; c++) { smin[c][threadIdx.x] = mn[c]; smax[c][threadIdx.x] = mx[c]; }
    __syncthreads();
    for (int s = 128; s > 0; s >>= 1) {
        if (threadIdx.x < s) {
#pragma unroll
            for (int c = 0; c < 3; c++) {
                smin[c][threadIdx.x] = fminf(smin[c][threadIdx.x], smin[c][threadIdx.x + s]);
                smax[c][threadIdx.x] = fmaxf(smax[c][threadIdx.x], smax[c][threadIdx.x + s]);
            }
        }
        __syncthreads();
    }
    float ctr[3], sz[3];
#pragma unroll
    for (int c = 0; c < 3; c++) {
        ctr[c] = 0.5f * (smin[c][0] + smax[c][0]);
        sz[c]  = smax[c][0] - ctr[c];
    }
    if (threadIdx.x == 0) {
#pragma unroll
        for (int c = 0; c < 3; c++) { csz[c * NBB + bb] = ctr[c]; csz[(3 + c) * NBB + bb] = sz[c]; }
    }
    for (int i = threadIdx.x; i < NV; i += 256) {
#pragma unroll
        for (int c = 0; c < 3; c++)
            v[((size_t)i * 3 + c) * NBB + bb] = (src[i * 3 + c] - ctr[c]) / sz[c];
        sulc[(size_t)i * NBB + bb] = 0.f;
    }
}

// ---------------- per-step: geometry -> feats[9] = (v, n, 0.5*lap) ----------------
// wave-per-vertex, lane = bb: all neighbor indices wave-uniform -> coalesced 256B loads
__global__ __launch_bounds__(256) void k_geom(const float* __restrict__ v,
                                              const int* __restrict__ deg,
                                              const int* __restrict__ nbrB,
                                              const int* __restrict__ nbrC,
                                              float* __restrict__ feat) {
    int lane = threadIdx.x & 63;
    int vi = rfl(blockIdx.x * 4 + (threadIdx.x >> 6));
    if (vi >= NV) return;
    float sgn = (lane < BATCH) ? 1.f : -1.f;   // rh: reversed winding flips face normals only
    float ax_ = v[((size_t)vi * 3 + 0) * NBB + lane];
    float ay_ = v[((size_t)vi * 3 + 1) * NBB + lane];
    float az_ = v[((size_t)vi * 3 + 2) * NBB + lane];
    float vnx = 0.f, vny = 0.f, vnz = 0.f, lx = 0.f, ly = 0.f, lz = 0.f;
    int d = rfl(deg[vi]);
    for (int k = 0; k < d; k++) {
        int iB = rfl(nbrB[vi * 6 + k]);
        int iC = rfl(nbrC[vi * 6 + k]);
        float bx = v[((size_t)iB * 3 + 0) * NBB + lane];
        float by = v[((size_t)iB * 3 + 1) * NBB + lane];
        float bz = v[((size_t)iB * 3 + 2) * NBB + lane];
        float cx = v[((size_t)iC * 3 + 0) * NBB + lane];
        float cy = v[((size_t)iC * 3 + 1) * NBB + lane];
        float cz = v[((size_t)iC * 3 + 2) * NBB + lane];
        float e1x = bx - ax_, e1y = by - ay_, e1z = bz - az_;   // B - A
        float e2x = cx - ax_, e2y = cy - ay_, e2z = cz - az_;   // C - A
        float fnx = e1y * e2z - e1z * e2y;                      // cross(B-A, C-A): face normal
        float fny = e1z * e2x - e1x * e2z;
        float fnz = e1x * e2y - e1y * e2x;
        vnx += fnx; vny += fny; vnz += fnz;
        float denom = sqrtf(fnx * fnx + fny * fny + fnz * fnz) + EPSV; // 2*area+eps: all cots share it
        // cot at B: edges (C-B, A-B)
        float ux = cx - bx, uy = cy - by, uz = cz - bz;
        float wx = ax_ - bx, wy = ay_ - by, wz = az_ - bz;
        float cB = (ux * wx + uy * wy + uz * wz) / denom;
        // cot at C: edges (A-C, B-C)
        float rx = ax_ - cx, ry = ay_ - cy, rz = az_ - cz;
        float sx = bx - cx, sy = by - cy, sz2 = bz - cz;
        float cC = (rx * sx + ry * sy + rz * sz2) / denom;
        // corner A receives cot(C)*(B-A) + cot(B)*(C-A)
        lx += cC * e1x + cB * e2x;
        ly += cC * e1y + cB * e2y;
        lz += cC * e1z + cB * e2z;
    }
    vnx *= sgn; vny *= sgn; vnz *= sgn;
    float nn = sqrtf(vnx * vnx + vny * vny + vnz * vnz) + EPSV;
    float* fp = feat + (size_t)vi * 9 * NBB + lane;
    fp[0 * NBB] = ax_; fp[1 * NBB] = ay_; fp[2 * NBB] = az_;
    fp[3 * NBB] = vnx / nn; fp[4 * NBB] = vny / nn; fp[5 * NBB] = vnz / nn;
    fp[6 * NBB] = 0.5f * lx; fp[7 * NBB] = 0.5f * ly; fp[8 * NBB] = 0.5f * lz;
}

// ---------------- per-step: layer1  h = relu(feats@W1s + mean_nbr(feats)@W1n + b1) ----------------
__global__ __launch_bounds__(256) void k_layer1(const float* __restrict__ feat,
                                                const int* __restrict__ deg,
                                                const int* __restrict__ nbrB,
                                                const float* __restrict__ W1s,
                                                const float* __restrict__ W1n,
                                                const float* __restrict__ b1,
                                                float* __restrict__ h) {
    __shared__ float sWs[144], sWn[144], sb[16];
    int t = threadIdx.x;
    if (t < 144) { sWs[t] = W1s[t]; sWn[t] = W1n[t]; }
    if (t < 16) sb[t] = b1[t];
    __syncthreads();
    int lane = t & 63;
    int vi = rfl(blockIdx.x * 4 + (t >> 6));
    if (vi >= NV) return;
    float own[9], m[9];
#pragma unroll
    for (int i = 0; i < 9; i++) {
        own[i] = feat[((size_t)vi * 9 + i) * NBB + lane];
        m[i] = 0.f;
    }
    int d = rfl(deg[vi]);
    for (int k = 0; k < d; k++) {
        int u = rfl(nbrB[vi * 6 + k]);
        const float* fu = feat + (size_t)u * 9 * NBB + lane;
#pragma unroll
        for (int i = 0; i < 9; i++) m[i] += fu[i * NBB];
    }
    float inv = 1.f / (float)d;
#pragma unroll
    for (int i = 0; i < 9; i++) m[i] *= inv;
    float* hp = h + (size_t)vi * 16 * NBB + lane;
#pragma unroll
    for (int j = 0; j < 16; j++) {
        float acc = sb[j];
#pragma unroll
        for (int i = 0; i < 9; i++) acc += own[i] * sWs[i * 16 + j] + m[i] * sWn[i * 16 + j];
        hp[j * NBB] = fmaxf(acc, 0.f);
    }
}

// ---------------- per-step: layer2 + output head + state update ----------------
__global__ __launch_bounds__(256) void k_layer2(const float* __restrict__ h,
                                                const float* __restrict__ feat,
                                                const int* __restrict__ deg,
                                                const int* __restrict__ nbrB,
                                                const float* __restrict__ W2s,
                                                const float* __restrict__ W2n,
                                                const float* __restrict__ b2,
                                                const float* __restrict__ Wo,
                                                const float* __restrict__ bo,
                                                float* __restrict__ v,
                                                float* __restrict__ sulc) {
    __shared__ float sWs[256], sWn[256], sb[16], sWo[48], sbo[3];
    int t = threadIdx.x;
    sWs[t] = W2s[t];
    sWn[t] = W2n[t];
    if (t < 16) sb[t] = b2[t];
    if (t < 48) sWo[t] = Wo[t];
    if (t < 3) sbo[t] = bo[t];
    __syncthreads();
    int lane = t & 63;
    int vi = rfl(blockIdx.x * 4 + (t >> 6));
    if (vi >= NV) return;
    float own[16], m[16];
#pragma unroll
    for (int i = 0; i < 16; i++) {
        own[i] = h[((size_t)vi * 16 + i) * NBB + lane];
        m[i] = 0.f;
    }
    int d = rfl(deg[vi]);
    for (int k = 0; k < d; k++) {
        int u = rfl(nbrB[vi * 6 + k]);
        const float* hu = h + (size_t)u * 16 * NBB + lane;
#pragma unroll
        for (int i = 0; i < 16; i++) m[i] += hu[i * NBB];
    }
    float inv = 1.f / (float)d;
#pragma unroll
    for (int i = 0; i < 16; i++) m[i] *= inv;
    float h2[16];
#pragma unroll
    for (int j = 0; j < 16; j++) {
        float acc = sb[j];
#pragma unroll
        for (int i = 0; i < 16; i++) acc += own[i] * sWs[i * 16 + j] + m[i] * sWn[i * 16 + j];
        h2[j] = fmaxf(acc, 0.f);
    }
    float dv[3];
#pragma unroll
    for (int c = 0; c < 3; c++) {
        float acc = sbo[c];
#pragma unroll
        for (int i = 0; i < 16; i++) acc += h2[i] * sWo[i * 3 + c];
        dv[c] = acc;
    }
    float* vp = v + (size_t)vi * 3 * NBB + lane;
    const float* np_ = feat + ((size_t)vi * 9 + 3) * NBB + lane;  // this step's normals
    vp[0 * NBB] += STEPSZ * dv[0];
    vp[1 * NBB] += STEPSZ * dv[1];
    vp[2 * NBB] += STEPSZ * dv[2];
    sulc[(size_t)vi * NBB + lane] +=
        STEPSZ * (np_[0 * NBB] * dv[0] + np_[1 * NBB] * dv[1] + np_[2 * NBB] * dv[2]);
}

// ---------------- output: (2,B,V,4) = (v*size, sulc) — transpose-out ----------------
__global__ __launch_bounds__(256) void k_out(const float* __restrict__ v,
                                             const float* __restrict__ sulc,
                                             const float* __restrict__ csz,
                                             float4* __restrict__ out) {
    int vi = blockIdx.x * 256 + threadIdx.x;
    int bb = blockIdx.y;
    if (vi >= NV) return;
    float4 o;
    o.x = v[((size_t)vi * 3 + 0) * NBB + bb] * csz[(3 + 0) * NBB + bb];
    o.y = v[((size_t)vi * 3 + 1) * NBB + bb] * csz[(3 + 1) * NBB + bb];
    o.z = v[((size_t)vi * 3 + 2) * NBB + bb] * csz[(3 + 2) * NBB + bb];
    o.w = sulc[(size_t)vi * NBB + bb];
    out[(size_t)bb * NV + vi] = o;   // bb = hemi*32 + b matches (2,B,V,4) layout
}

extern "C" void kernel_launch(void* const* d_in, const int* in_sizes, int n_in,
                              void* d_out, int out_size, void* d_ws, size_t ws_size,
                              hipStream_t stream) {
    const float* lh  = (const float*)d_in[0];
    const float* rh  = (const float*)d_in[1];
    const float* W1s = (const float*)d_in[2];
    const float* W1n = (const float*)d_in[3];
    const float* b1  = (const float*)d_in[4];
    const float* W2s = (const float*)d_in[5];
    const float* W2n = (const float*)d_in[6];
    const float* b2  = (const float*)d_in[7];
    const float* Wo  = (const float*)d_in[8];
    const float* bo  = (const float*)d_in[9];
    const int* faces = (const int*)d_in[10];

    float* ws   = (float*)d_ws;
    float* v    = ws + OFF_V;
    float* sulc = ws + OFF_SULC;
    float* feat = ws + OFF_FEAT;
    float* h    = ws + OFF_H;
    float* csz  = ws + OFF_CSZ;
    int* ibase  = (int*)(ws + OFF_INT);
    int* deg    = ibase;
    int* nbrB   = ibase + NV;
    int* nbrC   = ibase + NV + NV * 6;

    const int WPB = 4;                       // waves (vertices) per block
    dim3 gv((NV + WPB - 1) / WPB);           // 2561 blocks, wave-per-vertex

    k_zero_deg<<<(NV + 255) / 256, 256, 0, stream>>>(deg);
    k_build<<<(NF + 255) / 256, 256, 0, stream>>>(faces, deg, nbrB, nbrC);
    k_norm<<<NBB, 256, 0, stream>>>(lh, rh, v, sulc, csz);

    for (int s = 0; s < NSTEPS; s++) {
        k_geom<<<gv, 256, 0, stream>>>(v, deg, nbrB, nbrC, feat);
        k_layer1<<<gv, 256, 0, stream>>>(feat, deg, nbrB, W1s, W1n, b1, h);
        k_layer2<<<gv, 256, 0, stream>>>(h, feat, deg, nbrB, W2s, W2n, b2, Wo, bo, v, sulc);
    }
    k_out<<<dim3((NV + 255) / 256, NBB), 256, 0, stream>>>(v, sulc, csz, (float4*)d_out);
}